// Round 9
// baseline (155.175 us; speedup 1.0000x reference)
//
#include <hip/hip_runtime.h>
#include <cstdint>
#include <cstddef>

// ---------- types ----------
typedef __bf16 bf16;
typedef bf16  bf16x4  __attribute__((ext_vector_type(4)));
typedef bf16  bf16x8  __attribute__((ext_vector_type(8)));
typedef float floatx4 __attribute__((ext_vector_type(4)));

// Problem constants (reference: B=2, S=2048, D=1024, H=16, Dh=64)
#define BATCH 2
#define SEQ   2048
#define DIM   1024
#define NH    16
#define DH    64
#define D3    3072
#define MROWS 4096   // BATCH*SEQ

// async global->LDS, 16B per lane; LDS dest must be wave-uniform base + lane*16
__device__ __forceinline__ void gld16(void* lds, const void* gptr) {
  __builtin_amdgcn_global_load_lds(
      (const __attribute__((address_space(1))) unsigned int*)gptr,
      (__attribute__((address_space(3))) unsigned int*)lds, 16, 0, 0);
}

// ---------- kernel 1: merged prep ----------
// blocks [0,4096): x fp32 -> bf16        (1M float4)
// blocks [4096,7168): W_in  [1024][3072] -> W_in^T  bf16 (32x32 tiles)
// blocks [7168,8192): W_out [1024][1024] -> W_out^T bf16 (32x32 tiles)
__global__ __launch_bounds__(256) void k_prep(const float4* __restrict__ x,
                                              bf16* __restrict__ xb,
                                              const float* __restrict__ Wi,
                                              bf16* __restrict__ wti,
                                              const float* __restrict__ Wo,
                                              bf16* __restrict__ wto) {
  __shared__ float tile[32][33];
  const int bid = blockIdx.x;
  if (bid < 4096) {
    int i = bid * 256 + threadIdx.x;
    float4 v = x[i];
    bf16x4 o;
    o.x = (bf16)v.x; o.y = (bf16)v.y; o.z = (bf16)v.z; o.w = (bf16)v.w;
    *(bf16x4*)(xb + (size_t)i * 4) = o;
    return;
  }
  const float* W; bf16* Wt; int N, id;
  if (bid < 7168) { W = Wi; Wt = wti; N = 3072; id = bid - 4096; }
  else            { W = Wo; Wt = wto; N = 1024; id = bid - 7168; }
  const int nb = N / 32;
  int n0 = (id % nb) * 32, k0 = (id / nb) * 32;
  int tx = threadIdx.x & 31, ty = threadIdx.x >> 5;   // ty in [0,8)
#pragma unroll
  for (int i = 0; i < 4; i++)
    tile[ty + i * 8][tx] = W[(size_t)(k0 + ty + i * 8) * N + n0 + tx];
  __syncthreads();
#pragma unroll
  for (int i = 0; i < 4; i++)
    Wt[(size_t)(n0 + ty + i * 8) * 1024 + k0 + tx] = (bf16)tile[tx][ty + i * 8];
}

// ---------- kernel 2a: GEMM1  128x192, TWO-phase K-tile, 2 blocks/CU ----------
// r8 change: merge the 4 phases into 2 (24-MFMA clusters) -> barriers/K-tile
// 8 -> 4. Same fragments/indexing/swizzle/staging units/grid as the r5 winner.
// Issue points: P1 -> {stA(T+1,hi), stB(T+1,u1)}; P2 -> {stA(T+2,lo), stB(T+2,u0)}.
// vmcnt ledger: at head of T the newest 5 outstanding = stage(T+1).lo units
// (issued in T-1's P2) -> vmcnt(5) unchanged; vmcnt(0) only last tile.
// Race ledger: A.lo/B.u0 of buf[T&1] last ds_read in P1 (consumed by P1 MFMA's
// lgkm waits) -> overwrite issued in P2, >=1 barrier later. A.hi(bp^1) last read
// prev-iter P2; B.u1(bp^1) last read prev-iter P1 -> issues in this P1 are >=2
// barriers later. Conflict-free b128 swizzle (0 conflicts measured r0-r8).
__global__ __launch_bounds__(256, 2) void k_gemm1(const bf16* __restrict__ A,
                                                  const bf16* __restrict__ Bt,
                                                  bf16* __restrict__ qk,
                                                  bf16* __restrict__ vt) {
  constexpr int K = DIM;        // 1024
  constexpr int nk = K / 64;    // 16 K-tiles
  __shared__ __align__(16) bf16 As[2][128 * 64];   // 32 KB
  __shared__ __align__(16) bf16 Bs[2][192 * 64];   // 48 KB

  const int t = threadIdx.x, l = t & 63, w = t >> 6;
  const int q = l >> 4, mm = l & 15;
  const int wm = w >> 1, wn = w & 1;

  // XCD-aware 8x8 sub-grid: each XCD gets 8 A-panels x 8 B-panels (~5MB ~= L2).
  const int xcd = blockIdx.x & 7, j = blockIdx.x >> 3;
  const int by = ((xcd >> 1) << 3) + (j >> 3);     // [0,32)
  const int bx = ((xcd & 1) << 3) + (j & 7);       // [0,16)
  const int m0 = by * 128, n0 = bx * 192;

  auto stA = [&](int T, int up) {
    const int bp = T & 1;
#pragma unroll
    for (int i = 0; i < 2; i++) {
      int c = t + i * 256;                   // 512 chunks
      int rl = c >> 3, pos = c & 7;
      int row = ((rl >> 5) << 6) + (up << 5) + (rl & 31);
      int gs = pos ^ (row & 7);
      gld16((char*)(As[bp] + row * 64 + pos * 8),
            A + (size_t)(m0 + row) * K + T * 64 + gs * 8);
    }
  };
  auto stB = [&](int T, int up) {
    const int bp = T & 1;
#pragma unroll
    for (int i = 0; i < 3; i++) {
      int c = t + i * 256;                   // 768 chunks
      int rl = c >> 3, pos = c & 7;
      int row = up * 96 + rl;
      int gs = pos ^ (row & 7);
      gld16((char*)(Bs[bp] + row * 64 + pos * 8),
            Bt + (size_t)(n0 + row) * K + T * 64 + gs * 8);
    }
  };

  floatx4 acc[4][6] = {};                    // [mt 0..3][nt 0..5]

  stA(0, 0); stB(0, 0); stA(0, 1); stB(0, 1);
  stA(1, 0); stB(1, 0);

  for (int T = 0; T < nk; T++) {
    const int bp = T & 1;
    if (T + 1 < nk)
      asm volatile("s_waitcnt vmcnt(5)\n\ts_barrier" ::: "memory");
    else
      asm volatile("s_waitcnt vmcnt(0)\n\ts_barrier" ::: "memory");

    const bf16* Ab = As[bp] + wm * 64 * 64;
    const bf16* Bb = Bs[bp] + wn * 96 * 64;
    bf16x8 a0[2][2], a1[2][2], b0[3][2], b1[3][2];

    // ---------- P1: M0 x N(0:96) — 16 ds_reads, 24 MFMA ----------
#pragma unroll
    for (int mt = 0; mt < 2; mt++)
#pragma unroll
      for (int kk = 0; kk < 2; kk++)
        a0[mt][kk] = *(const bf16x8*)(Ab + (size_t)(mt * 16 + mm) * 64 +
                                      ((kk * 4 + q) ^ (mm & 7)) * 8);
#pragma unroll
    for (int nt = 0; nt < 3; nt++)
#pragma unroll
      for (int kk = 0; kk < 2; kk++) {
        b0[nt][kk] = *(const bf16x8*)(Bb + (size_t)(nt * 16 + mm) * 64 +
                                      ((kk * 4 + q) ^ (mm & 7)) * 8);
        b1[nt][kk] = *(const bf16x8*)(Bb + (size_t)((3 + nt) * 16 + mm) * 64 +
                                      ((kk * 4 + q) ^ (mm & 7)) * 8);
      }
    if (T + 1 < nk) { stA(T + 1, 1); stB(T + 1, 1); }
    asm volatile("s_barrier" ::: "memory");
    __builtin_amdgcn_s_setprio(1);
#pragma unroll
    for (int mt = 0; mt < 2; mt++)
#pragma unroll
      for (int nt = 0; nt < 3; nt++)
#pragma unroll
        for (int kk = 0; kk < 2; kk++) {
          acc[mt][nt] = __builtin_amdgcn_mfma_f32_16x16x32_bf16(
              a0[mt][kk], b0[nt][kk], acc[mt][nt], 0, 0, 0);
          acc[mt][3 + nt] = __builtin_amdgcn_mfma_f32_16x16x32_bf16(
              a0[mt][kk], b1[nt][kk], acc[mt][3 + nt], 0, 0, 0);
        }
    __builtin_amdgcn_s_setprio(0);
    asm volatile("s_barrier" ::: "memory");

    // ---------- P2: M1 x N(0:96) — 4 ds_reads, 24 MFMA ----------
#pragma unroll
    for (int mt = 0; mt < 2; mt++)
#pragma unroll
      for (int kk = 0; kk < 2; kk++)
        a1[mt][kk] = *(const bf16x8*)(Ab + (size_t)(32 + mt * 16 + mm) * 64 +
                                      ((kk * 4 + q) ^ (mm & 7)) * 8);
    if (T + 2 < nk) { stA(T + 2, 0); stB(T + 2, 0); }   // cur-buf regions dead since P1
    asm volatile("s_barrier" ::: "memory");
    __builtin_amdgcn_s_setprio(1);
#pragma unroll
    for (int mt = 0; mt < 2; mt++)
#pragma unroll
      for (int nt = 0; nt < 3; nt++)
#pragma unroll
        for (int kk = 0; kk < 2; kk++) {
          acc[2 + mt][nt] = __builtin_amdgcn_mfma_f32_16x16x32_bf16(
              a1[mt][kk], b0[nt][kk], acc[2 + mt][nt], 0, 0, 0);
          acc[2 + mt][3 + nt] = __builtin_amdgcn_mfma_f32_16x16x32_bf16(
              a1[mt][kk], b1[nt][kk], acc[2 + mt][3 + nt], 0, 0, 0);
        }
    __builtin_amdgcn_s_setprio(0);
    // loop head provides vmcnt + barrier
  }

  // epilogue: C/D layout col=lane&15, row=(lane>>4)*4+reg. qkv split at col 2048.
#pragma unroll
  for (int mt = 0; mt < 4; mt++)
#pragma unroll
    for (int nt = 0; nt < 6; nt++) {
      int row = m0 + wm * 64 + mt * 16 + q * 4;
      int col = n0 + wn * 96 + nt * 16 + mm;
      if (col < 2048) {
#pragma unroll
        for (int r = 0; r < 4; r++)
          qk[(size_t)(row + r) * 2048 + col] = (bf16)acc[mt][nt][r];
      } else {
        int d = col - 2048;                  // 0..1023
        int hh = d >> 6, dh = d & 63;
#pragma unroll
        for (int r = 0; r < 4; r++) {
          int rr = row + r;
          int bb = rr >> 11, s = rr & 2047;
          vt[((size_t)(bb * 16 + hh) * 64 + dh) * SEQ + s] = (bf16)acc[mt][nt][r];
        }
      }
    }
}

// ---------- kernel 2b: GEMM2  (unchanged from round 4 — ~10.7 us) ----------
__global__ __launch_bounds__(256, 2) void k_gemm2(const bf16* __restrict__ A,
                                                  const bf16* __restrict__ Bt,
                                                  float* __restrict__ C) {
  constexpr int K = DIM;        // 1024
  constexpr int nk = K / 64;    // 16 K-tiles
  constexpr int N = DIM;        // 1024
  __shared__ __align__(16) bf16 As[3][128 * 64];   // 48 KB
  __shared__ __align__(16) bf16 Bs[3][64 * 64];    // 24 KB

  const int t = threadIdx.x, l = t & 63, w = t >> 6;
  const int q = l >> 4, mm = l & 15;
  const int wm = w >> 1, wn = w & 1;

  // same XCD-aware 8x8 sub-grid as GEMM1 (grid is 32 M-panels x 16 N-panels)
  const int xcd = blockIdx.x & 7, j = blockIdx.x >> 3;
  const int by = ((xcd >> 1) << 3) + (j >> 3);     // [0,32)
  const int bx = ((xcd & 1) << 3) + (j & 7);       // [0,16)
  const int m0 = by * 128, n0 = bx * 64;

  auto stA2 = [&](int T) {
    const int bp = T % 3;
#pragma unroll
    for (int i = 0; i < 4; i++) {
      int c = t + i * 256;                   // 1024 chunks = 16 KB
      int row = c >> 3, pos = c & 7;
      int gs = pos ^ (row & 7);
      gld16((char*)(As[bp] + row * 64 + pos * 8),
            A + (size_t)(m0 + row) * K + T * 64 + gs * 8);
    }
  };
  auto stB2 = [&](int T) {
    const int bp = T % 3;
#pragma unroll
    for (int i = 0; i < 2; i++) {
      int c = t + i * 256;                   // 512 chunks = 8 KB
      int row = c >> 3, pos = c & 7;
      int gs = pos ^ (row & 7);
      gld16((char*)(Bs[bp] + row * 64 + pos * 8),
            Bt + (size_t)(n0 + row) * K + T * 64 + gs * 8);
    }
  };

  floatx4 acc[4][2] = {};                    // [mt 0..3][nt 0..1]

  stA2(0); stB2(0);                          // tile 0
  stA2(1); stB2(1);                          // tile 1 -> 12 loads outstanding

  for (int T = 0; T < nk; T++) {
    const int bp = T % 3;
    // head: st(T) landed; newest 6 = st(T+1) stay in flight.
    if (T + 1 < nk)
      asm volatile("s_waitcnt vmcnt(6)\n\ts_barrier" ::: "memory");
    else
      asm volatile("s_waitcnt vmcnt(0)\n\ts_barrier" ::: "memory");

    const bf16* Ab = As[bp] + wm * 64 * 64;
    const bf16* Bb = Bs[bp] + wn * 32 * 64;
    bf16x8 af[4][2], bf[2][2];

    // ---------- P1: mt 0-1 x nt 0-1 ----------
#pragma unroll
    for (int mt = 0; mt < 2; mt++)
#pragma unroll
      for (int kk = 0; kk < 2; kk++)
        af[mt][kk] = *(const bf16x8*)(Ab + (size_t)(mt * 16 + mm) * 64 +
                                      ((kk * 4 + q) ^ (mm & 7)) * 8);
#pragma unroll
    for (int nt = 0; nt < 2; nt++)
#pragma unroll
      for (int kk = 0; kk < 2; kk++)
        bf[nt][kk] = *(const bf16x8*)(Bb + (size_t)(nt * 16 + mm) * 64 +
                                      ((kk * 4 + q) ^ (mm & 7)) * 8);
    if (T + 2 < nk) stA2(T + 2);             // A-region of buf[(T+2)%3] dead since T-1 P2
    asm volatile("s_barrier" ::: "memory");
    __builtin_amdgcn_s_setprio(1);
#pragma unroll
    for (int mt = 0; mt < 2; mt++)
#pragma unroll
      for (int nt = 0; nt < 2; nt++)
#pragma unroll
        for (int kk = 0; kk < 2; kk++)
          acc[mt][nt] = __builtin_amdgcn_mfma_f32_16x16x32_bf16(
              af[mt][kk], bf[nt][kk], acc[mt][nt], 0, 0, 0);
    __builtin_amdgcn_s_setprio(0);
    asm volatile("s_barrier" ::: "memory");

    // ---------- P2: mt 2-3 x nt 0-1 ----------
#pragma unroll
    for (int mt = 0; mt < 2; mt++)
#pragma unroll
      for (int kk = 0; kk < 2; kk++)
        af[2 + mt][kk] = *(const bf16x8*)(Ab + (size_t)(32 + mt * 16 + mm) * 64 +
                                          ((kk * 4 + q) ^ (mm & 7)) * 8);
    if (T + 2 < nk) stB2(T + 2);             // B-region dead since T-1 P1
    asm volatile("s_barrier" ::: "memory");
    __builtin_amdgcn_s_setprio(1);
#pragma unroll
    for (int mt = 0; mt < 2; mt++)
#pragma unroll
      for (int nt = 0; nt < 2; nt++)
#pragma unroll
        for (int kk = 0; kk < 2; kk++)
          acc[2 + mt][nt] = __builtin_amdgcn_mfma_f32_16x16x32_bf16(
              af[2 + mt][kk], bf[nt][kk], acc[2 + mt][nt], 0, 0, 0);
    __builtin_amdgcn_s_setprio(0);
    // loop head provides vmcnt + barrier
  }

  // epilogue: C/D layout col=lane&15, row=(lane>>4)*4+reg
#pragma unroll
  for (int mt = 0; mt < 4; mt++)
#pragma unroll
    for (int nt = 0; nt < 2; nt++) {
      int row = m0 + wm * 64 + mt * 16 + q * 4;
      int col = n0 + wn * 32 + nt * 16 + mm;
#pragma unroll
      for (int r = 0; r < 4; r++)
        C[(size_t)(row + r) * N + col] = acc[mt][nt][r];
    }
}

// ---------- kernel 3: causal flash attention (64-row Q tile, dbuf K/V, fixed-max) ----------
// (unchanged from round 8 — balanced qt permutation, measured win: every CU gets
// exactly 66 iters from its 4 co-resident blocks {31-a, a, 23-a, 8+a}.)
__global__ __launch_bounds__(256, 4) void k_attn(const bf16* __restrict__ qk,
                                                 const bf16* __restrict__ vt,
                                                 bf16* __restrict__ out) {
  const int bx = blockIdx.x;
  const int g = bx >> 5, a = g & 7, bq = g >> 3;
  const int qt = (bq == 0) ? (31 - a) : (bq == 1) ? a : (bq == 2) ? (23 - a) : (8 + a);
  const int bh = bx & 31;
  const int b = bh >> 4, h = bh & 15;
  const int t = threadIdx.x, l = t & 63, w = t >> 6;
  const int q4 = l >> 4, mm = l & 15;
  const int sw = (mm >> 1) & 3;

  // LDS: union{ Qs[2][64][32] 8192 (dead after qf load) ; Ps[4w][16][40] 5120 }
  //      Ks: 2 x [2][64][32] (16384) ; Vs: 2 x [64][64] (16384)  == 40960 total
  __shared__ __align__(16) char lds[8192 + 16384 + 16384];
  bf16* Qs = (bf16*)lds;
  bf16* Ps = (bf16*)lds;                  // per-wave +w*640 elems, row stride 40
  bf16* Ks = (bf16*)(lds + 8192);         // buf bp at +bp*4096 elems
  bf16* Vs = (bf16*)(lds + 8192 + 16384);

  const size_t qkbase = (size_t)b * SEQ * 2048;
  const size_t vtbase = (size_t)bh * 64 * SEQ;

  // stage K (2x gld16, GEMM-style swizzle) + V^T (2x gld16, 8-chunk swizzle) into buf kt&1
  auto stage = [&](int kt) {
    const int bp = kt & 1;
#pragma unroll
    for (int i = 0; i < 2; i++) {
      int row = t >> 2, pos = t & 3;
      int g2 = pos ^ ((row >> 1) & 3);
      gld16((char*)(Ks + bp * 4096) + ((size_t)t + i * 256) * 16,
            qk + qkbase + (size_t)(kt * 64 + row) * 2048 + 1024 + h * 64 + i * 32 + g2 * 8);
    }
#pragma unroll
    for (int i = 0; i < 2; i++) {
      int c = t + i * 256;               // 512 chunks: row d = c>>3, slot cc = c&7
      int vr = c >> 3, vc = c & 7;
      int src = vc ^ (vr & 7);
      gld16((char*)(Vs + bp * 4096) + (size_t)c * 16,
            vt + vtbase + (size_t)vr * SEQ + kt * 64 + src * 8);
    }
  };

  { // stage Q tile once: 64 rows x 64 cols -> [ks][64][32] (unswizzled; read once)
    int row = t >> 2, col = (t & 3) * 8;
#pragma unroll
    for (int i = 0; i < 2; i++)
      gld16((char*)Qs + ((size_t)t + i * 256) * 16,
            qk + qkbase + (size_t)(qt * 64 + row) * 2048 + h * 64 + i * 32 + col);
  }
  stage(0);
  __syncthreads();                        // Q + stage(0) landed
  bf16x8 qf[2];
#pragma unroll
  for (int ks = 0; ks < 2; ks++) {
    qf[ks] = *(const bf16x8*)(Qs + (size_t)(ks * 64 + w * 16 + mm) * 32 + q4 * 8);
#pragma unroll
    for (int j = 0; j < 8; j++)           // 1/sqrt(64) * log2(e): exp2-domain softmax
      qf[ks][j] = (bf16)((float)qf[ks][j] * 0.18033688f);
  }
  __syncthreads();                        // all waves read Q before Ps overwrites it

  float l_i = 0.f;
  floatx4 oaccT[4] = {};                  // O^T: d = nt*16+q4*4+r, q-col = mm
  const int qloc = w * 16 + mm;           // lane's q row within tile
  const float FM = 24.0f;                 // fixed log2-domain max bound

  bf16* Pw = Ps + (size_t)w * 640;        // this wave's P region [16][40]

  for (int kt = 0; kt <= qt; kt++) {
    if (kt < qt) stage(kt + 1);           // in flight during this iter's compute
    const bf16* Kb = Ks + (kt & 1) * 4096;
    const bf16* Vb = Vs + (kt & 1) * 4096;

    // S^T tile: 64 k rows x 16 q cols per wave: mfma(A=K, B=Q)
    floatx4 sacc[4] = {};
#pragma unroll
    for (int ks = 0; ks < 2; ks++)
#pragma unroll
      for (int ct = 0; ct < 4; ct++) {
        bf16x8 kf = *(const bf16x8*)(Kb + (size_t)(ks * 64 + ct * 16 + mm) * 32 + (q4 ^ sw) * 8);
        sacc[ct] = __builtin_amdgcn_mfma_f32_16x16x32_bf16(kf, qf[ks], sacc[ct], 0, 0, 0);
      }

    // fixed-max softmax (log2 units): p = exp2(s - FM); mask -> 0 on diagonal tile
    bf16x4 pk[4];
    float rsum = 0.f;
    if (kt == qt) {
#pragma unroll
      for (int ct = 0; ct < 4; ct++)
#pragma unroll
        for (int r = 0; r < 4; r++) {
          float e = (ct * 16 + q4 * 4 + r > qloc)
                        ? 0.f : __builtin_amdgcn_exp2f(sacc[ct][r] - FM);
          pk[ct][r] = (bf16)e;
          rsum += e;
        }
    } else {
#pragma unroll
      for (int ct = 0; ct < 4; ct++)
#pragma unroll
        for (int r = 0; r < 4; r++) {
          float e = __builtin_amdgcn_exp2f(sacc[ct][r] - FM);
          pk[ct][r] = (bf16)e;
          rsum += e;
        }
    }
    rsum += __shfl_xor(rsum, 16, 64);
    rsum += __shfl_xor(rsum, 32, 64);
    l_i += rsum;

    // P^T -> B-operand layout via half-width LDS buffer (two 32-col halves)
#pragma unroll
    for (int ks = 0; ks < 2; ks++) {
      *(bf16x4*)(Pw + (size_t)mm * 40 + q4 * 4)      = pk[ks * 2 + 0];
      *(bf16x4*)(Pw + (size_t)mm * 40 + 16 + q4 * 4) = pk[ks * 2 + 1];
      bf16x8 pf = *(const bf16x8*)(Pw + (size_t)mm * 40 + q4 * 8);
#pragma unroll
      for (int nt = 0; nt < 4; nt++) {
        int chunk = (ks * 4 + q4) ^ (mm & 7);    // undo staging swizzle
        bf16x8 vf = *(const bf16x8*)(Vb + (size_t)(nt * 16 + mm) * 64 + chunk * 8);
        oaccT[nt] = __builtin_amdgcn_mfma_f32_16x16x32_bf16(vf, pf, oaccT[nt], 0, 0, 0);
      }
    }

    if (kt < qt) __syncthreads();          // drains stage(kt+1); guards bufs
  }

  // epilogue: lane owns one q row; normalize and store 4x bf16x4
  float inv = 1.0f / l_i;
  int qrow = qt * 64 + qloc;
  bf16* orow = out + ((size_t)b * SEQ + qrow) * DIM + h * 64;
#pragma unroll
  for (int nt = 0; nt < 4; nt++) {
    bf16x4 o4;
#pragma unroll
    for (int r = 0; r < 4; r++) o4[r] = (bf16)(oaccT[nt][r] * inv);
    *(bf16x4*)(orow + nt * 16 + q4 * 4) = o4;
  }
}

// ---------- launch ----------
extern "C" void kernel_launch(void* const* d_in, const int* in_sizes, int n_in,
                              void* d_out, int out_size, void* d_ws, size_t ws_size,
                              hipStream_t stream) {
  const float* x     = (const float*)d_in[0];   // [2,2048,1024]
  const float* W_in  = (const float*)d_in[1];   // [1024,3072]
  const float* W_out = (const float*)d_in[2];   // [1024,1024]
  float* out = (float*)d_out;                   // [2,2048,1024]

  char* ws = (char*)d_ws;
  bf16* xb   = (bf16*)(ws);                       //  8 MB: x bf16 [4096][1024] (reused: attn out)
  bf16* wti  = (bf16*)(ws + 8388608);             //  6 MB: W_in^T  [3072][1024]
  bf16* wto  = (bf16*)(ws + 14680064);            //  2 MB: W_out^T [1024][1024]
  bf16* qkb  = (bf16*)(ws + 16777216);            // 16 MB: QK bf16 [4096][2048]
  bf16* vtb  = (bf16*)(ws + 33554432);            //  8 MB: V^T bf16 [32*64][2048]
  bf16* attn = xb;                                //  reuse: xb dead after GEMM1

  k_prep<<<8192, 256, 0, stream>>>((const float4*)x, xb, W_in, wti, W_out, wto);
  // GEMM1: M=4096 N=3072 K=1024; 128x192 2-phase, 512 blocks = 2/CU, XCD 8x8 sub-grid.
  k_gemm1<<<512, 256, 0, stream>>>(xb, wti, qkb, vtb);
  // attn: 1024 blocks = 32 bh x 32 q-tiles (64 rows), 4 blocks/CU, balanced qt perm.
  k_attn<<<1024, 256, 0, stream>>>(qkb, vtb, attn);
  // GEMM2: M=4096 N=1024 K=1024; 128x64 2-phase BK=64 3-buf, 512 blocks = 2/CU.
  k_gemm2<<<512, 256, 0, stream>>>(attn, wto, out);
}

// Round 10
// 153.699 us; speedup vs baseline: 1.0096x; 1.0096x over previous
//
#include <hip/hip_runtime.h>
#include <cstdint>
#include <cstddef>

// ---------- types ----------
typedef __bf16 bf16;
typedef bf16  bf16x4  __attribute__((ext_vector_type(4)));
typedef bf16  bf16x8  __attribute__((ext_vector_type(8)));
typedef float floatx4 __attribute__((ext_vector_type(4)));

// Problem constants (reference: B=2, S=2048, D=1024, H=16, Dh=64)
#define BATCH 2
#define SEQ   2048
#define DIM   1024
#define NH    16
#define DH    64
#define D3    3072
#define MROWS 4096   // BATCH*SEQ

// async global->LDS, 16B per lane; LDS dest must be wave-uniform base + lane*16
__device__ __forceinline__ void gld16(void* lds, const void* gptr) {
  __builtin_amdgcn_global_load_lds(
      (const __attribute__((address_space(1))) unsigned int*)gptr,
      (__attribute__((address_space(3))) unsigned int*)lds, 16, 0, 0);
}

// ---------- kernel 1: merged prep ----------
// blocks [0,4096): x fp32 -> bf16        (1M float4)
// blocks [4096,7168): W_in  [1024][3072] -> W_in^T  bf16 (32x32 tiles)
// blocks [7168,8192): W_out [1024][1024] -> W_out^T bf16 (32x32 tiles)
__global__ __launch_bounds__(256) void k_prep(const float4* __restrict__ x,
                                              bf16* __restrict__ xb,
                                              const float* __restrict__ Wi,
                                              bf16* __restrict__ wti,
                                              const float* __restrict__ Wo,
                                              bf16* __restrict__ wto) {
  __shared__ float tile[32][33];
  const int bid = blockIdx.x;
  if (bid < 4096) {
    int i = bid * 256 + threadIdx.x;
    float4 v = x[i];
    bf16x4 o;
    o.x = (bf16)v.x; o.y = (bf16)v.y; o.z = (bf16)v.z; o.w = (bf16)v.w;
    *(bf16x4*)(xb + (size_t)i * 4) = o;
    return;
  }
  const float* W; bf16* Wt; int N, id;
  if (bid < 7168) { W = Wi; Wt = wti; N = 3072; id = bid - 4096; }
  else            { W = Wo; Wt = wto; N = 1024; id = bid - 7168; }
  const int nb = N / 32;
  int n0 = (id % nb) * 32, k0 = (id / nb) * 32;
  int tx = threadIdx.x & 31, ty = threadIdx.x >> 5;   // ty in [0,8)
#pragma unroll
  for (int i = 0; i < 4; i++)
    tile[ty + i * 8][tx] = W[(size_t)(k0 + ty + i * 8) * N + n0 + tx];
  __syncthreads();
#pragma unroll
  for (int i = 0; i < 4; i++)
    Wt[(size_t)(n0 + ty + i * 8) * 1024 + k0 + tx] = (bf16)tile[tx][ty + i * 8];
}

// ---------- kernel 2a: GEMM1  128x192 4-phase, 2 blocks/CU (T2+T3+T4+T5) ----------
// REVERTED to the r5/r8 4-phase body — the measured optimum of its family:
// beat 1-phase (r0: 45.6us), 8-phase@256^2 (r1: 52.8us), and 2-phase (r9:
// +1.3us). At 2 blocks/CU the cross-block overlap absorbs the 8-barrier/K-tile
// sync tax; merging phases lengthened the P1 lgkm-serial head instead.
__global__ __launch_bounds__(256, 2) void k_gemm1(const bf16* __restrict__ A,
                                                  const bf16* __restrict__ Bt,
                                                  bf16* __restrict__ qk,
                                                  bf16* __restrict__ vt) {
  constexpr int K = DIM;        // 1024
  constexpr int nk = K / 64;    // 16 K-tiles
  __shared__ __align__(16) bf16 As[2][128 * 64];   // 32 KB
  __shared__ __align__(16) bf16 Bs[2][192 * 64];   // 48 KB

  const int t = threadIdx.x, l = t & 63, w = t >> 6;
  const int q = l >> 4, mm = l & 15;
  const int wm = w >> 1, wn = w & 1;

  // XCD-aware 8x8 sub-grid: each XCD gets 8 A-panels x 8 B-panels (~5MB ~= L2).
  const int xcd = blockIdx.x & 7, j = blockIdx.x >> 3;
  const int by = ((xcd >> 1) << 3) + (j >> 3);     // [0,32)
  const int bx = ((xcd & 1) << 3) + (j & 7);       // [0,16)
  const int m0 = by * 128, n0 = bx * 192;

  auto stA = [&](int T, int up) {
    const int bp = T & 1;
#pragma unroll
    for (int i = 0; i < 2; i++) {
      int c = t + i * 256;                   // 512 chunks
      int rl = c >> 3, pos = c & 7;
      int row = ((rl >> 5) << 6) + (up << 5) + (rl & 31);
      int gs = pos ^ (row & 7);
      gld16((char*)(As[bp] + row * 64 + pos * 8),
            A + (size_t)(m0 + row) * K + T * 64 + gs * 8);
    }
  };
  auto stB = [&](int T, int up) {
    const int bp = T & 1;
#pragma unroll
    for (int i = 0; i < 3; i++) {
      int c = t + i * 256;                   // 768 chunks
      int rl = c >> 3, pos = c & 7;
      int row = up * 96 + rl;
      int gs = pos ^ (row & 7);
      gld16((char*)(Bs[bp] + row * 64 + pos * 8),
            Bt + (size_t)(n0 + row) * K + T * 64 + gs * 8);
    }
  };

  floatx4 acc[4][6] = {};                    // [mt 0..3][nt 0..5]

  stA(0, 0); stB(0, 0); stA(0, 1); stB(0, 1);
  stA(1, 0); stB(1, 0);

  for (int T = 0; T < nk; T++) {
    const int bp = T & 1;
    if (T + 1 < nk)
      asm volatile("s_waitcnt vmcnt(5)\n\ts_barrier" ::: "memory");
    else
      asm volatile("s_waitcnt vmcnt(0)\n\ts_barrier" ::: "memory");

    const bf16* Ab = As[bp] + wm * 64 * 64;
    const bf16* Bb = Bs[bp] + wn * 96 * 64;
    bf16x8 a0[2][2], a1[2][2], b0[3][2], b1[3][2];

    // ---------- P1: M0 x N(0:48) ----------
#pragma unroll
    for (int mt = 0; mt < 2; mt++)
#pragma unroll
      for (int kk = 0; kk < 2; kk++)
        a0[mt][kk] = *(const bf16x8*)(Ab + (size_t)(mt * 16 + mm) * 64 +
                                      ((kk * 4 + q) ^ (mm & 7)) * 8);
#pragma unroll
    for (int nt = 0; nt < 3; nt++)
#pragma unroll
      for (int kk = 0; kk < 2; kk++)
        b0[nt][kk] = *(const bf16x8*)(Bb + (size_t)(nt * 16 + mm) * 64 +
                                      ((kk * 4 + q) ^ (mm & 7)) * 8);
    if (T + 1 < nk) stA(T + 1, 1);
    asm volatile("s_barrier" ::: "memory");
    __builtin_amdgcn_s_setprio(1);
#pragma unroll
    for (int mt = 0; mt < 2; mt++)
#pragma unroll
      for (int nt = 0; nt < 3; nt++)
#pragma unroll
        for (int kk = 0; kk < 2; kk++)
          acc[mt][nt] = __builtin_amdgcn_mfma_f32_16x16x32_bf16(
              a0[mt][kk], b0[nt][kk], acc[mt][nt], 0, 0, 0);
    __builtin_amdgcn_s_setprio(0);
    asm volatile("s_barrier" ::: "memory");

    // ---------- P2: M0 x N(48:96) ----------
#pragma unroll
    for (int nt = 0; nt < 3; nt++)
#pragma unroll
      for (int kk = 0; kk < 2; kk++)
        b1[nt][kk] = *(const bf16x8*)(Bb + (size_t)((3 + nt) * 16 + mm) * 64 +
                                      ((kk * 4 + q) ^ (mm & 7)) * 8);
    if (T + 1 < nk) stB(T + 1, 1);
    asm volatile("s_barrier" ::: "memory");
    __builtin_amdgcn_s_setprio(1);
#pragma unroll
    for (int mt = 0; mt < 2; mt++)
#pragma unroll
      for (int nt = 0; nt < 3; nt++)
#pragma unroll
        for (int kk = 0; kk < 2; kk++)
          acc[mt][3 + nt] = __builtin_amdgcn_mfma_f32_16x16x32_bf16(
              a0[mt][kk], b1[nt][kk], acc[mt][3 + nt], 0, 0, 0);
    __builtin_amdgcn_s_setprio(0);
    asm volatile("s_barrier" ::: "memory");

    // ---------- P3: M1 x N(0:48) ----------
#pragma unroll
    for (int mt = 0; mt < 2; mt++)
#pragma unroll
      for (int kk = 0; kk < 2; kk++)
        a1[mt][kk] = *(const bf16x8*)(Ab + (size_t)(32 + mt * 16 + mm) * 64 +
                                      ((kk * 4 + q) ^ (mm & 7)) * 8);
    if (T + 2 < nk) stA(T + 2, 0);           // overwrites cur A.lo (dead since P1)
    asm volatile("s_barrier" ::: "memory");
    __builtin_amdgcn_s_setprio(1);
#pragma unroll
    for (int mt = 0; mt < 2; mt++)
#pragma unroll
      for (int nt = 0; nt < 3; nt++)
#pragma unroll
        for (int kk = 0; kk < 2; kk++)
          acc[2 + mt][nt] = __builtin_amdgcn_mfma_f32_16x16x32_bf16(
              a1[mt][kk], b0[nt][kk], acc[2 + mt][nt], 0, 0, 0);
    __builtin_amdgcn_s_setprio(0);
    asm volatile("s_barrier" ::: "memory");

    // ---------- P4: M1 x N(48:96) ----------
    if (T + 2 < nk) stB(T + 2, 0);           // overwrites cur B.u0 (dead since P2)
    asm volatile("s_barrier" ::: "memory");
    __builtin_amdgcn_s_setprio(1);
#pragma unroll
    for (int mt = 0; mt < 2; mt++)
#pragma unroll
      for (int nt = 0; nt < 3; nt++)
#pragma unroll
        for (int kk = 0; kk < 2; kk++)
          acc[2 + mt][3 + nt] = __builtin_amdgcn_mfma_f32_16x16x32_bf16(
              a1[mt][kk], b1[nt][kk], acc[2 + mt][3 + nt], 0, 0, 0);
    __builtin_amdgcn_s_setprio(0);
    // loop head provides vmcnt + barrier
  }

  // epilogue: C/D layout col=lane&15, row=(lane>>4)*4+reg. qkv split at col 2048.
#pragma unroll
  for (int mt = 0; mt < 4; mt++)
#pragma unroll
    for (int nt = 0; nt < 6; nt++) {
      int row = m0 + wm * 64 + mt * 16 + q * 4;
      int col = n0 + wn * 96 + nt * 16 + mm;
      if (col < 2048) {
#pragma unroll
        for (int r = 0; r < 4; r++)
          qk[(size_t)(row + r) * 2048 + col] = (bf16)acc[mt][nt][r];
      } else {
        int d = col - 2048;                  // 0..1023
        int hh = d >> 6, dh = d & 63;
#pragma unroll
        for (int r = 0; r < 4; r++) {
          int rr = row + r;
          int bb = rr >> 11, s = rr & 2047;
          vt[((size_t)(bb * 16 + hh) * 64 + dh) * SEQ + s] = (bf16)acc[mt][nt][r];
        }
      }
    }
}

// ---------- kernel 2b: GEMM2  (unchanged from round 4 — ~10.7 us, at LDS-issue roofline) ----------
__global__ __launch_bounds__(256, 2) void k_gemm2(const bf16* __restrict__ A,
                                                  const bf16* __restrict__ Bt,
                                                  float* __restrict__ C) {
  constexpr int K = DIM;        // 1024
  constexpr int nk = K / 64;    // 16 K-tiles
  constexpr int N = DIM;        // 1024
  __shared__ __align__(16) bf16 As[3][128 * 64];   // 48 KB
  __shared__ __align__(16) bf16 Bs[3][64 * 64];    // 24 KB

  const int t = threadIdx.x, l = t & 63, w = t >> 6;
  const int q = l >> 4, mm = l & 15;
  const int wm = w >> 1, wn = w & 1;

  // same XCD-aware 8x8 sub-grid as GEMM1 (grid is 32 M-panels x 16 N-panels)
  const int xcd = blockIdx.x & 7, j = blockIdx.x >> 3;
  const int by = ((xcd >> 1) << 3) + (j >> 3);     // [0,32)
  const int bx = ((xcd & 1) << 3) + (j & 7);       // [0,16)
  const int m0 = by * 128, n0 = bx * 64;

  auto stA2 = [&](int T) {
    const int bp = T % 3;
#pragma unroll
    for (int i = 0; i < 4; i++) {
      int c = t + i * 256;                   // 1024 chunks = 16 KB
      int row = c >> 3, pos = c & 7;
      int gs = pos ^ (row & 7);
      gld16((char*)(As[bp] + row * 64 + pos * 8),
            A + (size_t)(m0 + row) * K + T * 64 + gs * 8);
    }
  };
  auto stB2 = [&](int T) {
    const int bp = T % 3;
#pragma unroll
    for (int i = 0; i < 2; i++) {
      int c = t + i * 256;                   // 512 chunks = 8 KB
      int row = c >> 3, pos = c & 7;
      int gs = pos ^ (row & 7);
      gld16((char*)(Bs[bp] + row * 64 + pos * 8),
            Bt + (size_t)(n0 + row) * K + T * 64 + gs * 8);
    }
  };

  floatx4 acc[4][2] = {};                    // [mt 0..3][nt 0..1]

  stA2(0); stB2(0);                          // tile 0
  stA2(1); stB2(1);                          // tile 1 -> 12 loads outstanding

  for (int T = 0; T < nk; T++) {
    const int bp = T % 3;
    // head: st(T) landed; newest 6 = st(T+1) stay in flight.
    if (T + 1 < nk)
      asm volatile("s_waitcnt vmcnt(6)\n\ts_barrier" ::: "memory");
    else
      asm volatile("s_waitcnt vmcnt(0)\n\ts_barrier" ::: "memory");

    const bf16* Ab = As[bp] + wm * 64 * 64;
    const bf16* Bb = Bs[bp] + wn * 32 * 64;
    bf16x8 af[4][2], bf[2][2];

    // ---------- P1: mt 0-1 x nt 0-1 ----------
#pragma unroll
    for (int mt = 0; mt < 2; mt++)
#pragma unroll
      for (int kk = 0; kk < 2; kk++)
        af[mt][kk] = *(const bf16x8*)(Ab + (size_t)(mt * 16 + mm) * 64 +
                                      ((kk * 4 + q) ^ (mm & 7)) * 8);
#pragma unroll
    for (int nt = 0; nt < 2; nt++)
#pragma unroll
      for (int kk = 0; kk < 2; kk++)
        bf[nt][kk] = *(const bf16x8*)(Bb + (size_t)(nt * 16 + mm) * 64 +
                                      ((kk * 4 + q) ^ (mm & 7)) * 8);
    if (T + 2 < nk) stA2(T + 2);             // A-region of buf[(T+2)%3] dead since T-1 P2
    asm volatile("s_barrier" ::: "memory");
    __builtin_amdgcn_s_setprio(1);
#pragma unroll
    for (int mt = 0; mt < 2; mt++)
#pragma unroll
      for (int nt = 0; nt < 2; nt++)
#pragma unroll
        for (int kk = 0; kk < 2; kk++)
          acc[mt][nt] = __builtin_amdgcn_mfma_f32_16x16x32_bf16(
              af[mt][kk], bf[nt][kk], acc[mt][nt], 0, 0, 0);
    __builtin_amdgcn_s_setprio(0);
    asm volatile("s_barrier" ::: "memory");

    // ---------- P2: mt 2-3 x nt 0-1 ----------
#pragma unroll
    for (int mt = 0; mt < 2; mt++)
#pragma unroll
      for (int kk = 0; kk < 2; kk++)
        af[2 + mt][kk] = *(const bf16x8*)(Ab + (size_t)(32 + mt * 16 + mm) * 64 +
                                          ((kk * 4 + q) ^ (mm & 7)) * 8);
    if (T + 2 < nk) stB2(T + 2);             // B-region dead since T-1 P1
    asm volatile("s_barrier" ::: "memory");
    __builtin_amdgcn_s_setprio(1);
#pragma unroll
    for (int mt = 0; mt < 2; mt++)
#pragma unroll
      for (int nt = 0; nt < 2; nt++)
#pragma unroll
        for (int kk = 0; kk < 2; kk++)
          acc[2 + mt][nt] = __builtin_amdgcn_mfma_f32_16x16x32_bf16(
              af[2 + mt][kk], bf[nt][kk], acc[2 + mt][nt], 0, 0, 0);
    __builtin_amdgcn_s_setprio(0);
    // loop head provides vmcnt + barrier
  }

  // epilogue: C/D layout col=lane&15, row=(lane>>4)*4+reg
#pragma unroll
  for (int mt = 0; mt < 4; mt++)
#pragma unroll
    for (int nt = 0; nt < 2; nt++) {
      int row = m0 + wm * 64 + mt * 16 + q * 4;
      int col = n0 + wn * 32 + nt * 16 + mm;
#pragma unroll
      for (int r = 0; r < 4; r++)
        C[(size_t)(row + r) * N + col] = acc[mt][nt][r];
    }
}

// ---------- kernel 3: causal flash attention (64-row Q tile, dbuf K/V, fixed-max) ----------
// (r8 version — balanced qt permutation: every CU gets exactly 66 iters from its
// 4 co-resident blocks {31-a, a, 23-a, 8+a}; measured win 156.6 -> 153.8.)
__global__ __launch_bounds__(256, 4) void k_attn(const bf16* __restrict__ qk,
                                                 const bf16* __restrict__ vt,
                                                 bf16* __restrict__ out) {
  const int bx = blockIdx.x;
  const int g = bx >> 5, a = g & 7, bq = g >> 3;
  const int qt = (bq == 0) ? (31 - a) : (bq == 1) ? a : (bq == 2) ? (23 - a) : (8 + a);
  const int bh = bx & 31;
  const int b = bh >> 4, h = bh & 15;
  const int t = threadIdx.x, l = t & 63, w = t >> 6;
  const int q4 = l >> 4, mm = l & 15;
  const int sw = (mm >> 1) & 3;

  // LDS: union{ Qs[2][64][32] 8192 (dead after qf load) ; Ps[4w][16][40] 5120 }
  //      Ks: 2 x [2][64][32] (16384) ; Vs: 2 x [64][64] (16384)  == 40960 total
  __shared__ __align__(16) char lds[8192 + 16384 + 16384];
  bf16* Qs = (bf16*)lds;
  bf16* Ps = (bf16*)lds;                  // per-wave +w*640 elems, row stride 40
  bf16* Ks = (bf16*)(lds + 8192);         // buf bp at +bp*4096 elems
  bf16* Vs = (bf16*)(lds + 8192 + 16384);

  const size_t qkbase = (size_t)b * SEQ * 2048;
  const size_t vtbase = (size_t)bh * 64 * SEQ;

  // stage K (2x gld16, GEMM-style swizzle) + V^T (2x gld16, 8-chunk swizzle) into buf kt&1
  auto stage = [&](int kt) {
    const int bp = kt & 1;
#pragma unroll
    for (int i = 0; i < 2; i++) {
      int row = t >> 2, pos = t & 3;
      int g2 = pos ^ ((row >> 1) & 3);
      gld16((char*)(Ks + bp * 4096) + ((size_t)t + i * 256) * 16,
            qk + qkbase + (size_t)(kt * 64 + row) * 2048 + 1024 + h * 64 + i * 32 + g2 * 8);
    }
#pragma unroll
    for (int i = 0; i < 2; i++) {
      int c = t + i * 256;               // 512 chunks: row d = c>>3, slot cc = c&7
      int vr = c >> 3, vc = c & 7;
      int src = vc ^ (vr & 7);
      gld16((char*)(Vs + bp * 4096) + (size_t)c * 16,
            vt + vtbase + (size_t)vr * SEQ + kt * 64 + src * 8);
    }
  };

  { // stage Q tile once: 64 rows x 64 cols -> [ks][64][32] (unswizzled; read once)
    int row = t >> 2, col = (t & 3) * 8;
#pragma unroll
    for (int i = 0; i < 2; i++)
      gld16((char*)Qs + ((size_t)t + i * 256) * 16,
            qk + qkbase + (size_t)(qt * 64 + row) * 2048 + h * 64 + i * 32 + col);
  }
  stage(0);
  __syncthreads();                        // Q + stage(0) landed
  bf16x8 qf[2];
#pragma unroll
  for (int ks = 0; ks < 2; ks++) {
    qf[ks] = *(const bf16x8*)(Qs + (size_t)(ks * 64 + w * 16 + mm) * 32 + q4 * 8);
#pragma unroll
    for (int j = 0; j < 8; j++)           // 1/sqrt(64) * log2(e): exp2-domain softmax
      qf[ks][j] = (bf16)((float)qf[ks][j] * 0.18033688f);
  }
  __syncthreads();                        // all waves read Q before Ps overwrites it

  float l_i = 0.f;
  floatx4 oaccT[4] = {};                  // O^T: d = nt*16+q4*4+r, q-col = mm
  const int qloc = w * 16 + mm;           // lane's q row within tile
  const float FM = 24.0f;                 // fixed log2-domain max bound

  bf16* Pw = Ps + (size_t)w * 640;        // this wave's P region [16][40]

  for (int kt = 0; kt <= qt; kt++) {
    if (kt < qt) stage(kt + 1);           // in flight during this iter's compute
    const bf16* Kb = Ks + (kt & 1) * 4096;
    const bf16* Vb = Vs + (kt & 1) * 4096;

    // S^T tile: 64 k rows x 16 q cols per wave: mfma(A=K, B=Q)
    floatx4 sacc[4] = {};
#pragma unroll
    for (int ks = 0; ks < 2; ks++)
#pragma unroll
      for (int ct = 0; ct < 4; ct++) {
        bf16x8 kf = *(const bf16x8*)(Kb + (size_t)(ks * 64 + ct * 16 + mm) * 32 + (q4 ^ sw) * 8);
        sacc[ct] = __builtin_amdgcn_mfma_f32_16x16x32_bf16(kf, qf[ks], sacc[ct], 0, 0, 0);
      }

    // fixed-max softmax (log2 units): p = exp2(s - FM); mask -> 0 on diagonal tile
    bf16x4 pk[4];
    float rsum = 0.f;
    if (kt == qt) {
#pragma unroll
      for (int ct = 0; ct < 4; ct++)
#pragma unroll
        for (int r = 0; r < 4; r++) {
          float e = (ct * 16 + q4 * 4 + r > qloc)
                        ? 0.f : __builtin_amdgcn_exp2f(sacc[ct][r] - FM);
          pk[ct][r] = (bf16)e;
          rsum += e;
        }
    } else {
#pragma unroll
      for (int ct = 0; ct < 4; ct++)
#pragma unroll
        for (int r = 0; r < 4; r++) {
          float e = __builtin_amdgcn_exp2f(sacc[ct][r] - FM);
          pk[ct][r] = (bf16)e;
          rsum += e;
        }
    }
    rsum += __shfl_xor(rsum, 16, 64);
    rsum += __shfl_xor(rsum, 32, 64);
    l_i += rsum;

    // P^T -> B-operand layout via half-width LDS buffer (two 32-col halves)
#pragma unroll
    for (int ks = 0; ks < 2; ks++) {
      *(bf16x4*)(Pw + (size_t)mm * 40 + q4 * 4)      = pk[ks * 2 + 0];
      *(bf16x4*)(Pw + (size_t)mm * 40 + 16 + q4 * 4) = pk[ks * 2 + 1];
      bf16x8 pf = *(const bf16x8*)(Pw + (size_t)mm * 40 + q4 * 8);
#pragma unroll
      for (int nt = 0; nt < 4; nt++) {
        int chunk = (ks * 4 + q4) ^ (mm & 7);    // undo staging swizzle
        bf16x8 vf = *(const bf16x8*)(Vb + (size_t)(nt * 16 + mm) * 64 + chunk * 8);
        oaccT[nt] = __builtin_amdgcn_mfma_f32_16x16x32_bf16(vf, pf, oaccT[nt], 0, 0, 0);
      }
    }

    if (kt < qt) __syncthreads();          // drains stage(kt+1); guards bufs
  }

  // epilogue: lane owns one q row; normalize and store 4x bf16x4
  float inv = 1.0f / l_i;
  int qrow = qt * 64 + qloc;
  bf16* orow = out + ((size_t)b * SEQ + qrow) * DIM + h * 64;
#pragma unroll
  for (int nt = 0; nt < 4; nt++) {
    bf16x4 o4;
#pragma unroll
    for (int r = 0; r < 4; r++) o4[r] = (bf16)(oaccT[nt][r] * inv);
    *(bf16x4*)(orow + nt * 16 + q4 * 4) = o4;
  }
}

// ---------- launch ----------
extern "C" void kernel_launch(void* const* d_in, const int* in_sizes, int n_in,
                              void* d_out, int out_size, void* d_ws, size_t ws_size,
                              hipStream_t stream) {
  const float* x     = (const float*)d_in[0];   // [2,2048,1024]
  const float* W_in  = (const float*)d_in[1];   // [1024,3072]
  const float* W_out = (const float*)d_in[2];   // [1024,1024]
  float* out = (float*)d_out;                   // [2,2048,1024]

  char* ws = (char*)d_ws;
  bf16* xb   = (bf16*)(ws);                       //  8 MB: x bf16 [4096][1024] (reused: attn out)
  bf16* wti  = (bf16*)(ws + 8388608);             //  6 MB: W_in^T  [3072][1024]
  bf16* wto  = (bf16*)(ws + 14680064);            //  2 MB: W_out^T [1024][1024]
  bf16* qkb  = (bf16*)(ws + 16777216);            // 16 MB: QK bf16 [4096][2048]
  bf16* vtb  = (bf16*)(ws + 33554432);            //  8 MB: V^T bf16 [32*64][2048]
  bf16* attn = xb;                                //  reuse: xb dead after GEMM1

  k_prep<<<8192, 256, 0, stream>>>((const float4*)x, xb, W_in, wti, W_out, wto);
  // GEMM1: M=4096 N=3072 K=1024; 128x192 4-phase, 512 blocks = 2/CU, XCD 8x8 sub-grid.
  k_gemm1<<<512, 256, 0, stream>>>(xb, wti, qkb, vtb);
  // attn: 1024 blocks = 32 bh x 32 q-tiles (64 rows), 4 blocks/CU, balanced qt perm.
  k_attn<<<1024, 256, 0, stream>>>(qkb, vtb, attn);
  // GEMM2: M=4096 N=1024 K=1024; 128x64 2-phase BK=64 3-buf, 512 blocks = 2/CU.
  k_gemm2<<<512, 256, 0, stream>>>(attn, wto, out);
}